// Round 4
// baseline (44.847 us; speedup 1.0000x reference)
//
#include <hip/hip_runtime.h>
#include <math.h>

#define NMODES 4096
#define NGRID  8192
#define BATCH  16
#define NPTS   131072

// ---------------------------------------------------------------------------
// Fully fused NFFT type-2. One workgroup = one (batch, point-chunk) pair.
// Each block: build h = (-1)^j * pad(f_hat/phi_hat) in LDS, 13 in-place DIF
// radix-2 stages (bit-reversed result), then interpolate its 4096 points
// directly from LDS (bit-reversal + (-1)^t sign folded into the gather).
// ---------------------------------------------------------------------------
__global__ __launch_bounds__(1024) void nfft_fused_kernel(
    const float* __restrict__ x, const float* __restrict__ fr,
    const float* __restrict__ fi, float* __restrict__ out, int cplx)
{
    __shared__ float2 buf[NGRID];    // 64 KB

    const int b   = blockIdx.x >> 5;    // batch
    const int blk = blockIdx.x & 31;    // point chunk within batch
    const int tid = threadIdx.x;

    // ---- build h = (-1)^j * pad(f_hat / phi_hat) ----
    for (int j = tid; j < NGRID; j += 1024) {
        float2 v = make_float2(0.0f, 0.0f);
        if (j >= 2048 && j < 6144) {
            int   fidx = j - 2048;                    // f_hat index 0..4095
            float k    = (float)(fidx - 2048);        // mode index -2048..2047
            float t    = k * 7.66990393942820614e-4f; // 2*pi*k/n
            float z    = 4.0f * sqrtf(22.2066099024510563f - t * t);
            // I0(z) asymptotic (z in [17.8, 18.9]) -> rel err ~1e-7
            float iz = 1.0f / z;
            float p  = 1.0f + iz * (0.125f + iz * (0.0703125f +
                       iz * (0.0732421875f + iz * 0.112152099609375f)));
            float phi = __expf(z) * p * rsqrtf(6.28318530717958648f * z);
            float s   = (fidx & 1) ? -1.0f : 1.0f;    // (-1)^j (2048 even)
            float inv = s / phi;
            v.x = fr[b * NMODES + fidx] * inv;
            v.y = fi[b * NMODES + fidx] * inv;
        }
        buf[j] = v;
    }
    __syncthreads();

    // ---- 13 in-place radix-2 DIF stages (result bit-reversed) ----
    for (int s = 12; s >= 0; --s) {
        const int   half = 1 << s;
        const float ascl = -3.14159265358979323846f / (float)half;
        for (int i = tid; i < 4096; i += 1024) {
            int pos = i & (half - 1);
            int idx = ((i ^ pos) << 1) | pos;
            float sn, cs;
            __sincosf(ascl * (float)pos, &sn, &cs);
            float2 a = buf[idx];
            float2 c = buf[idx + half];
            buf[idx] = make_float2(a.x + c.x, a.y + c.y);
            float2 d = make_float2(a.x - c.x, a.y - c.y);
            buf[idx + half] = make_float2(d.x * cs - d.y * sn,
                                          d.x * sn + d.y * cs);
        }
        __syncthreads();
    }

    // ---- interpolation: g[t] = (-1)^t * buf[brev13(t)] ----
    const int base = b * NPTS + blk * 4096;
    for (int p = tid; p < 4096; p += 1024) {
        float xv  = x[base + p];
        int   c   = (int)ceilf(xv * 8192.0f);   // exact scale (2^13)
        int   id0 = c - 4;
        float re = 0.0f, im = 0.0f;
#pragma unroll
        for (int l = 0; l < 8; ++l) {
            int   ind  = id0 + l;
            float t    = xv - (float)ind * 1.220703125e-4f;  // x - ind/n
            float u    = t * 8192.0f;                        // n*k
            float arg2 = 16.0f - u * u;                      // m^2 - (nk)^2
            float w    = 0.0f;
            if (arg2 > 0.0f) {                               // NaN / 0 -> 0
                float arg = sqrtf(arg2);
                float z   = 4.71238898038468986f * arg;      // b*arg
                float ez  = __expf(z);
                float em  = __expf(-z);
                // sinh(z)/(pi*arg) = (e^z - e^-z) * (1/(2*pi)) / arg
                w = (ez - em) * 0.15915494309189533577f / arg;
            }
            if (ind & 1) w = -w;              // (-1)^wrapped (4096 even)
            int wr = (ind + 4096) & (NGRID - 1);             // periodic wrap
            int rb = (int)(__brev((unsigned)wr) >> 19);      // un-bit-reverse
            float2 gv = buf[rb];
            re = fmaf(w, gv.x, re);
            im = fmaf(w, gv.y, im);
        }
        if (cplx) ((float2*)out)[base + p] = make_float2(re, im);
        else      out[base + p] = re;
    }
}

extern "C" void kernel_launch(void* const* d_in, const int* in_sizes, int n_in,
                              void* d_out, int out_size, void* d_ws, size_t ws_size,
                              hipStream_t stream) {
    (void)in_sizes; (void)n_in; (void)d_ws; (void)ws_size;
    const float* x  = (const float*)d_in[0];
    const float* fr = (const float*)d_in[1];
    const float* fi = (const float*)d_in[2];

    // Output layout: real-only (out_size == B*M) vs interleaved complex
    // (out_size == 2*B*M). Branch is deterministic (out_size is fixed).
    const int cplx = (out_size >= BATCH * NPTS * 2) ? 1 : 0;

    nfft_fused_kernel<<<BATCH * 32, 1024, 0, stream>>>(
        x, fr, fi, (float*)d_out, cplx);
}

// Round 6
// 34.514 us; speedup vs baseline: 1.2994x; 1.2994x over previous
//
#include <hip/hip_runtime.h>
#include <math.h>

#define NMODES 4096
#define NGRID  8192
#define BATCH  16
#define NPTS   131072

// ---------------------------------------------------------------------------
// Deconvolution factor: (-1)^fidx / phi_hat(fidx), I0 asymptotic (z~18).
// ---------------------------------------------------------------------------
__device__ __forceinline__ float deconv_signed(int fidx) {
    float k = (float)(fidx - 2048);
    float t = k * 7.66990393942820614e-4f;                 // 2*pi*k/n
    float z = 4.0f * sqrtf(22.2066099024510563f - t * t);  // m*sqrt(b^2-t^2)
    float iz = 1.0f / z;
    float p  = 1.0f + iz * (0.125f + iz * (0.0703125f +
               iz * (0.0732421875f + iz * 0.112152099609375f)));
    float phi = __expf(z) * p * rsqrtf(6.28318530717958648f * z);
    float s = (fidx & 1) ? -1.0f : 1.0f;
    return s / phi;
}

// ---------------------------------------------------------------------------
// Kernel A: one block per batch. Build h=(-1)^j*pad(f/phi) scattered to
// bit-reversed LDS positions, 13 in-place DIT stages (natural-order output),
// store g[t] = (-1)^t * H[t] coalesced to global scratch.
// ---------------------------------------------------------------------------
__global__ __launch_bounds__(1024) void nfft_fft_kernel(
    const float* __restrict__ fr, const float* __restrict__ fi,
    float2* __restrict__ g)
{
    __shared__ float2 buf[NGRID];    // 64 KB
    const int b   = blockIdx.x;
    const int tid = threadIdx.x;

    for (int j = tid; j < NGRID; j += 1024) {
        float2 v = make_float2(0.0f, 0.0f);
        if (j >= 2048 && j < 6144) {
            int fidx = j - 2048;
            float inv = deconv_signed(fidx);
            v.x = fr[b * NMODES + fidx] * inv;
            v.y = fi[b * NMODES + fidx] * inv;
        }
        int rb = (int)(__brev((unsigned)j) >> 19);  // 13-bit reversal
        buf[rb] = v;
    }
    __syncthreads();

    // 13 radix-2 DIT stages (bit-reversed input -> natural output)
    for (int s = 0; s <= 12; ++s) {
        const int   half = 1 << s;
        const float ascl = -3.14159265358979323846f / (float)half;
        for (int i = tid; i < 4096; i += 1024) {
            int pos = i & (half - 1);
            int idx = ((i ^ pos) << 1) | pos;
            float sn, cs;
            __sincosf(ascl * (float)pos, &sn, &cs);
            float2 a = buf[idx];
            float2 t = buf[idx + half];
            float2 bt = make_float2(t.x * cs - t.y * sn,
                                    t.x * sn + t.y * cs);
            buf[idx]        = make_float2(a.x + bt.x, a.y + bt.y);
            buf[idx + half] = make_float2(a.x - bt.x, a.y - bt.y);
        }
        __syncthreads();
    }

    for (int t = tid; t < NGRID; t += 1024) {
        float2 v = buf[t];
        if (t & 1) { v.x = -v.x; v.y = -v.y; }
        g[b * NGRID + t] = v;
    }
}

// ---------------------------------------------------------------------------
// Kernel B: stage one batch's g (64 KB, float4 loads), interpolate 4096
// points per block. 8 contiguous taps (with the reference's +n/2 half-shift
// folded into the base index); 3 trans ops per tap.
// ---------------------------------------------------------------------------
__global__ __launch_bounds__(1024) void nfft_interp_kernel(
    const float* __restrict__ x, const float2* __restrict__ g,
    float* __restrict__ out, int cplx)
{
    __shared__ float2 gl[NGRID];     // 64 KB
    const int b   = blockIdx.x >> 5;
    const int blk = blockIdx.x & 31;

    const float4* gs = (const float4*)(g + b * NGRID);
    float4*       gd = (float4*)gl;
    for (int i = threadIdx.x; i < NGRID / 2; i += 1024) gd[i] = gs[i];
    __syncthreads();

    const int base = b * NPTS + blk * 4096;
    for (int p = threadIdx.x; p < 4096; p += 1024) {
        float xv   = x[base + p];
        float fl   = xv * 8192.0f;                 // exact (2^13 scale)
        int   c    = (int)ceilf(fl);
        float frac = (float)c - fl;                // in [0,1)
        // wrapped base = (c - 4 + n/2) mod n; +8192 keeps it non-negative
        int   wr0  = (c + 4092 + 8192) & (NGRID - 1);
        float re = 0.0f, im = 0.0f;
#pragma unroll
        for (int l = 0; l < 8; ++l) {
            float u    = (float)(4 - l) - frac;    // n*x - ind
            float arg2 = 16.0f - u * u;            // m^2 - u^2
            float w    = 0.0f;
            if (arg2 > 0.0f) {                     // NaN / arg==0 -> 0
                float r   = rsqrtf(arg2);          // 1/arg
                float arg = arg2 * r;              // arg
                float z   = 4.71238898038468986f * arg;
                float ez  = __expf(z);
                float em  = __expf(-z);
                w = (ez - em) * 0.15915494309189533577f * r;  // sinh/(pi*arg)
            }
            float2 gv = gl[(wr0 + l) & (NGRID - 1)];
            re = fmaf(w, gv.x, re);
            im = fmaf(w, gv.y, im);
        }
        if (cplx) ((float2*)out)[base + p] = make_float2(re, im);
        else      out[base + p] = re;
    }
}

// ---------------------------------------------------------------------------
// Fallback: fully fused single kernel (proven in R4) if d_ws is too small.
// ---------------------------------------------------------------------------
__global__ __launch_bounds__(1024) void nfft_fused_kernel(
    const float* __restrict__ x, const float* __restrict__ fr,
    const float* __restrict__ fi, float* __restrict__ out, int cplx)
{
    __shared__ float2 buf[NGRID];
    const int b   = blockIdx.x >> 5;
    const int blk = blockIdx.x & 31;
    const int tid = threadIdx.x;

    for (int j = tid; j < NGRID; j += 1024) {
        float2 v = make_float2(0.0f, 0.0f);
        if (j >= 2048 && j < 6144) {
            int fidx = j - 2048;
            float inv = deconv_signed(fidx);
            v.x = fr[b * NMODES + fidx] * inv;
            v.y = fi[b * NMODES + fidx] * inv;
        }
        buf[j] = v;
    }
    __syncthreads();

    for (int s = 12; s >= 0; --s) {
        const int   half = 1 << s;
        const float ascl = -3.14159265358979323846f / (float)half;
        for (int i = tid; i < 4096; i += 1024) {
            int pos = i & (half - 1);
            int idx = ((i ^ pos) << 1) | pos;
            float sn, cs;
            __sincosf(ascl * (float)pos, &sn, &cs);
            float2 a = buf[idx];
            float2 c = buf[idx + half];
            buf[idx] = make_float2(a.x + c.x, a.y + c.y);
            float2 d = make_float2(a.x - c.x, a.y - c.y);
            buf[idx + half] = make_float2(d.x * cs - d.y * sn,
                                          d.x * sn + d.y * cs);
        }
        __syncthreads();
    }

    const int base = b * NPTS + blk * 4096;
    for (int p = tid; p < 4096; p += 1024) {
        float xv   = x[base + p];
        float fl   = xv * 8192.0f;
        int   c    = (int)ceilf(fl);
        float frac = (float)c - fl;
        float re = 0.0f, im = 0.0f;
#pragma unroll
        for (int l = 0; l < 8; ++l) {
            int   ind  = c - 4 + l;
            float u    = (float)(4 - l) - frac;
            float arg2 = 16.0f - u * u;
            float w    = 0.0f;
            if (arg2 > 0.0f) {
                float r   = rsqrtf(arg2);
                float arg = arg2 * r;
                float z   = 4.71238898038468986f * arg;
                float ez  = __expf(z);
                float em  = __expf(-z);
                w = (ez - em) * 0.15915494309189533577f * r;
            }
            if (ind & 1) w = -w;
            int wr = (ind + 4096) & (NGRID - 1);
            int rb = (int)(__brev((unsigned)wr) >> 19);
            float2 gv = buf[rb];
            re = fmaf(w, gv.x, re);
            im = fmaf(w, gv.y, im);
        }
        if (cplx) ((float2*)out)[base + p] = make_float2(re, im);
        else      out[base + p] = re;
    }
}

extern "C" void kernel_launch(void* const* d_in, const int* in_sizes, int n_in,
                              void* d_out, int out_size, void* d_ws, size_t ws_size,
                              hipStream_t stream) {
    (void)in_sizes; (void)n_in;
    const float* x  = (const float*)d_in[0];
    const float* fr = (const float*)d_in[1];
    const float* fi = (const float*)d_in[2];

    const int cplx = (out_size >= BATCH * NPTS * 2) ? 1 : 0;
    const size_t g_bytes = (size_t)BATCH * NGRID * sizeof(float2);  // 1 MB

    if (ws_size >= g_bytes) {
        float2* g = (float2*)d_ws;
        nfft_fft_kernel<<<BATCH, 1024, 0, stream>>>(fr, fi, g);
        nfft_interp_kernel<<<BATCH * 32, 1024, 0, stream>>>(
            x, g, (float*)d_out, cplx);
    } else {
        nfft_fused_kernel<<<BATCH * 32, 1024, 0, stream>>>(
            x, fr, fi, (float*)d_out, cplx);
    }
}

// Round 7
// 34.168 us; speedup vs baseline: 1.3125x; 1.0101x over previous
//
#include <hip/hip_runtime.h>
#include <math.h>

#define NMODES 4096
#define NGRID  8192
#define BATCH  16
#define NPTS   131072

// ---------------------------------------------------------------------------
// Hardware twiddle: v_sin_f32 / v_cos_f32 take input in REVOLUTIONS.
// turns in (-0.5, 0] here -> no range reduction needed (vs ~35-instr
// __sincosf/__ocml_sincos_f32 with full payload handling).
// ---------------------------------------------------------------------------
__device__ __forceinline__ void tw_sincos_turns(float turns, float* sn, float* cs) {
    *sn = __builtin_amdgcn_sinf(turns);
    *cs = __builtin_amdgcn_cosf(turns);
}

// ---------------------------------------------------------------------------
// Deconvolution factor: (-1)^fidx / phi_hat(fidx), I0 asymptotic (z~18).
// ---------------------------------------------------------------------------
__device__ __forceinline__ float deconv_signed(int fidx) {
    float k = (float)(fidx - 2048);
    float t = k * 7.66990393942820614e-4f;                 // 2*pi*k/n
    float z = 4.0f * sqrtf(22.2066099024510563f - t * t);  // m*sqrt(b^2-t^2)
    float iz = 1.0f / z;
    float p  = 1.0f + iz * (0.125f + iz * (0.0703125f +
               iz * (0.0732421875f + iz * 0.112152099609375f)));
    float phi = __expf(z) * p * rsqrtf(6.28318530717958648f * z);
    float s = (fidx & 1) ? -1.0f : 1.0f;
    return s / phi;
}

// ---------------------------------------------------------------------------
// Kernel A: one block per batch. Build h=(-1)^j*pad(f/phi) scattered to
// bit-reversed LDS positions, 13 in-place DIT stages (natural-order output),
// store g[t] = (-1)^t * H[t] coalesced to global scratch.
// ---------------------------------------------------------------------------
__global__ __launch_bounds__(1024) void nfft_fft_kernel(
    const float* __restrict__ fr, const float* __restrict__ fi,
    float2* __restrict__ g)
{
    __shared__ float2 buf[NGRID];    // 64 KB
    const int b   = blockIdx.x;
    const int tid = threadIdx.x;

    for (int j = tid; j < NGRID; j += 1024) {
        float2 v = make_float2(0.0f, 0.0f);
        if (j >= 2048 && j < 6144) {
            int fidx = j - 2048;
            float inv = deconv_signed(fidx);
            v.x = fr[b * NMODES + fidx] * inv;
            v.y = fi[b * NMODES + fidx] * inv;
        }
        int rb = (int)(__brev((unsigned)j) >> 19);  // 13-bit reversal
        buf[rb] = v;
    }
    __syncthreads();

    // 13 radix-2 DIT stages (bit-reversed input -> natural output)
    for (int s = 0; s <= 12; ++s) {
        const int   half = 1 << s;
        const float tscl = -0.5f / (float)half;   // turns per pos
#pragma unroll
        for (int ii = 0; ii < 4; ++ii) {
            int i = tid + ii * 1024;
            int pos = i & (half - 1);
            int idx = ((i ^ pos) << 1) | pos;
            float sn, cs;
            tw_sincos_turns(tscl * (float)pos, &sn, &cs);
            float2 a = buf[idx];
            float2 t = buf[idx + half];
            float2 bt = make_float2(t.x * cs - t.y * sn,
                                    t.x * sn + t.y * cs);
            buf[idx]        = make_float2(a.x + bt.x, a.y + bt.y);
            buf[idx + half] = make_float2(a.x - bt.x, a.y - bt.y);
        }
        __syncthreads();
    }

    for (int t = tid; t < NGRID; t += 1024) {
        float2 v = buf[t];
        if (t & 1) { v.x = -v.x; v.y = -v.y; }
        g[b * NGRID + t] = v;
    }
}

// ---------------------------------------------------------------------------
// Kernel B: stage one batch's g (64 KB, float4 loads), interpolate 4096
// points per block. 8 contiguous taps (+n/2 half-shift folded into base).
// ---------------------------------------------------------------------------
__global__ __launch_bounds__(1024) void nfft_interp_kernel(
    const float* __restrict__ x, const float2* __restrict__ g,
    float* __restrict__ out, int cplx)
{
    __shared__ float2 gl[NGRID];     // 64 KB
    const int b   = blockIdx.x >> 5;
    const int blk = blockIdx.x & 31;

    const float4* gs = (const float4*)(g + b * NGRID);
    float4*       gd = (float4*)gl;
    for (int i = threadIdx.x; i < NGRID / 2; i += 1024) gd[i] = gs[i];
    __syncthreads();

    const int base = b * NPTS + blk * 4096;
    for (int p = threadIdx.x; p < 4096; p += 1024) {
        float xv   = x[base + p];
        float fl   = xv * 8192.0f;                 // exact (2^13 scale)
        int   c    = (int)ceilf(fl);
        float frac = (float)c - fl;                // in [0,1)
        // wrapped base = (c - 4 + n/2) mod n
        int   wr0  = (c + 4092 + 8192) & (NGRID - 1);
        float re = 0.0f, im = 0.0f;
#pragma unroll
        for (int l = 0; l < 8; ++l) {
            float u    = (float)(4 - l) - frac;    // n*x - ind
            float arg2 = 16.0f - u * u;            // m^2 - u^2
            float w    = 0.0f;
            if (arg2 > 0.0f) {                     // NaN / arg==0 -> 0
                float r   = rsqrtf(arg2);          // 1/arg
                float arg = arg2 * r;              // arg
                float z   = 4.71238898038468986f * arg;
                float ez  = __expf(z);
                float em  = __expf(-z);
                w = (ez - em) * 0.15915494309189533577f * r;  // sinh/(pi*arg)
            }
            float2 gv = gl[(wr0 + l) & (NGRID - 1)];
            re = fmaf(w, gv.x, re);
            im = fmaf(w, gv.y, im);
        }
        if (cplx) ((float2*)out)[base + p] = make_float2(re, im);
        else      out[base + p] = re;
    }
}

// ---------------------------------------------------------------------------
// Fallback: fully fused single kernel (proven in R4) if d_ws is too small.
// ---------------------------------------------------------------------------
__global__ __launch_bounds__(1024) void nfft_fused_kernel(
    const float* __restrict__ x, const float* __restrict__ fr,
    const float* __restrict__ fi, float* __restrict__ out, int cplx)
{
    __shared__ float2 buf[NGRID];
    const int b   = blockIdx.x >> 5;
    const int blk = blockIdx.x & 31;
    const int tid = threadIdx.x;

    for (int j = tid; j < NGRID; j += 1024) {
        float2 v = make_float2(0.0f, 0.0f);
        if (j >= 2048 && j < 6144) {
            int fidx = j - 2048;
            float inv = deconv_signed(fidx);
            v.x = fr[b * NMODES + fidx] * inv;
            v.y = fi[b * NMODES + fidx] * inv;
        }
        buf[j] = v;
    }
    __syncthreads();

    for (int s = 12; s >= 0; --s) {
        const int   half = 1 << s;
        const float tscl = -0.5f / (float)half;
#pragma unroll
        for (int ii = 0; ii < 4; ++ii) {
            int i = tid + ii * 1024;
            int pos = i & (half - 1);
            int idx = ((i ^ pos) << 1) | pos;
            float sn, cs;
            tw_sincos_turns(tscl * (float)pos, &sn, &cs);
            float2 a = buf[idx];
            float2 c = buf[idx + half];
            buf[idx] = make_float2(a.x + c.x, a.y + c.y);
            float2 d = make_float2(a.x - c.x, a.y - c.y);
            buf[idx + half] = make_float2(d.x * cs - d.y * sn,
                                          d.x * sn + d.y * cs);
        }
        __syncthreads();
    }

    const int base = b * NPTS + blk * 4096;
    for (int p = tid; p < 4096; p += 1024) {
        float xv   = x[base + p];
        float fl   = xv * 8192.0f;
        int   c    = (int)ceilf(fl);
        float frac = (float)c - fl;
        float re = 0.0f, im = 0.0f;
#pragma unroll
        for (int l = 0; l < 8; ++l) {
            int   ind  = c - 4 + l;
            float u    = (float)(4 - l) - frac;
            float arg2 = 16.0f - u * u;
            float w    = 0.0f;
            if (arg2 > 0.0f) {
                float r   = rsqrtf(arg2);
                float arg = arg2 * r;
                float z   = 4.71238898038468986f * arg;
                float ez  = __expf(z);
                float em  = __expf(-z);
                w = (ez - em) * 0.15915494309189533577f * r;
            }
            if (ind & 1) w = -w;
            int wr = (ind + 4096) & (NGRID - 1);
            int rb = (int)(__brev((unsigned)wr) >> 19);
            float2 gv = buf[rb];
            re = fmaf(w, gv.x, re);
            im = fmaf(w, gv.y, im);
        }
        if (cplx) ((float2*)out)[base + p] = make_float2(re, im);
        else      out[base + p] = re;
    }
}

extern "C" void kernel_launch(void* const* d_in, const int* in_sizes, int n_in,
                              void* d_out, int out_size, void* d_ws, size_t ws_size,
                              hipStream_t stream) {
    (void)in_sizes; (void)n_in;
    const float* x  = (const float*)d_in[0];
    const float* fr = (const float*)d_in[1];
    const float* fi = (const float*)d_in[2];

    const int cplx = (out_size >= BATCH * NPTS * 2) ? 1 : 0;
    const size_t g_bytes = (size_t)BATCH * NGRID * sizeof(float2);  // 1 MB

    if (ws_size >= g_bytes) {
        float2* g = (float2*)d_ws;
        nfft_fft_kernel<<<BATCH, 1024, 0, stream>>>(fr, fi, g);
        nfft_interp_kernel<<<BATCH * 32, 1024, 0, stream>>>(
            x, g, (float*)d_out, cplx);
    } else {
        nfft_fused_kernel<<<BATCH * 32, 1024, 0, stream>>>(
            x, fr, fi, (float*)d_out, cplx);
    }
}